// Round 14
// baseline (128.938 us; speedup 1.0000x reference)
//
#include <hip/hip_runtime.h>

typedef __bf16 bf16;
typedef _Float16 f16;
typedef f16 f16x4 __attribute__((ext_vector_type(4)));
typedef f16 f16x8 __attribute__((ext_vector_type(8)));
typedef float f32x4 __attribute__((ext_vector_type(4)));

#define MFMA_FP(a, b, c) __builtin_amdgcn_mfma_f32_16x16x32_f16((a), (b), (c), 0, 0, 0)

static constexpr int Bn = 8, T = 2048, C = 1024, H = 128;
static constexpr int M = Bn * T; // 16384

// ---------------------------------------------------------------------------
// Kernel 0: transpose  W[C][H] fp32 -> wt [3][H][C] fp16 (stacked 384 x C)
// ---------------------------------------------------------------------------
__global__ __launch_bounds__(256) void kwt(const float* __restrict__ Wq,
                                           const float* __restrict__ Wk,
                                           const float* __restrict__ Wv,
                                           f16* __restrict__ wt) {
  __shared__ float tl[32][33];
  const int w = blockIdx.z;
  const float* src = (w == 0) ? Wq : (w == 1) ? Wk : Wv;
  f16* dh = wt + (size_t)w * H * C;
  const int k0 = blockIdx.x * 32, n0 = blockIdx.y * 32;
  const int tx = threadIdx.x & 31, ty = threadIdx.x >> 5; // 32 x 8
  for (int i = ty; i < 32; i += 8) tl[i][tx] = src[(size_t)(k0 + i) * H + n0 + tx];
  __syncthreads();
  for (int i = ty; i < 32; i += 8)
    dh[(size_t)(n0 + i) * C + k0 + tx] = (f16)tl[tx][i];
}

// ---------------------------------------------------------------------------
// Kernel 1: QKV projection — LDS-FREE.  All operands direct L2->registers.
// No __shared__, no __syncthreads: waves fully independent, latency hidden by
// 12 resident waves/CU + software-pipelined K-loop (load k+1 while MFMA k).
// grid (M/64, 3) = 768 blocks = 3/CU.  Block: 64m x 128n (nh picks q/k/v).
// 4 waves (2m x 2n); wave = 32m x 64n (mt=2, nt=4), acc = 32 VGPR.
// Co-resident blocks (consecutive x, same nh) share B rows and wave-cols
// share A rows at the same k -> L1/L2 hits; traffic is the new (lower) floor.
// A (x fp32) cvt->fp16 in-register after load; f32 accumulate in MFMA.
// ---------------------------------------------------------------------------
__global__ __launch_bounds__(256, 3) void proj_kernel(const float* __restrict__ x,
                                                      const f16* __restrict__ wt,
                                                      f16* __restrict__ qo,
                                                      f16* __restrict__ ko,
                                                      f16* __restrict__ vt) {
  const int tid = threadIdx.x;
  const int lane = tid & 63, g = lane >> 4, r16 = lane & 15;
  const int wave = tid >> 6, wr = wave >> 1, wc = wave & 1;
  const int m0 = blockIdx.x * 64;
  const int nh = blockIdx.y;                  // 0=q, 1=k, 2=v

  // per-lane row pointers (k-contiguous frags: lane (g,r16) reads 8 elems at g*8)
  const float* xr[2];
  const f16* wrow[4];
#pragma unroll
  for (int mt = 0; mt < 2; ++mt)
    xr[mt] = x + (size_t)(m0 + wr * 32 + mt * 16 + r16) * C + g * 8;
#pragma unroll
  for (int nt = 0; nt < 4; ++nt)
    wrow[nt] = wt + (size_t)(nh * 128 + wc * 64 + nt * 16 + r16) * C + g * 8;

  f32x4 acc[2][4] = {};

  // software pipeline: cur regs compute, next regs load
  f32x4 a0[2], a1[2], a0n[2], a1n[2];
  f16x8 bc[4], bn[4];
#pragma unroll
  for (int mt = 0; mt < 2; ++mt) {
    a0[mt] = *(const f32x4*)(xr[mt]);
    a1[mt] = *(const f32x4*)(xr[mt] + 4);
  }
#pragma unroll
  for (int nt = 0; nt < 4; ++nt) bc[nt] = *(const f16x8*)(wrow[nt]);

  for (int k = 0; k < C; k += 32) {
    if (k + 32 < C) {
#pragma unroll
      for (int mt = 0; mt < 2; ++mt) {
        a0n[mt] = *(const f32x4*)(xr[mt] + k + 32);
        a1n[mt] = *(const f32x4*)(xr[mt] + k + 36);
      }
#pragma unroll
      for (int nt = 0; nt < 4; ++nt) bn[nt] = *(const f16x8*)(wrow[nt] + k + 32);
    }
    f16x8 af[2];
#pragma unroll
    for (int mt = 0; mt < 2; ++mt)
#pragma unroll
      for (int j = 0; j < 4; ++j) {
        af[mt][j] = (f16)a0[mt][j];
        af[mt][4 + j] = (f16)a1[mt][j];
      }
#pragma unroll
    for (int mt = 0; mt < 2; ++mt)
#pragma unroll
      for (int nt = 0; nt < 4; ++nt)
        acc[mt][nt] = MFMA_FP(af[mt], bc[nt], acc[mt][nt]);
#pragma unroll
    for (int mt = 0; mt < 2; ++mt) { a0[mt] = a0n[mt]; a1[mt] = a1n[mt]; }
#pragma unroll
    for (int nt = 0; nt < 4; ++nt) bc[nt] = bn[nt];
  }

  // epilogue.  C/D frag: col = lane&15, row = (lane>>4)*4 + reg  [m89]
  if (nh < 2) {
    f16* dst = nh ? ko : qo;
#pragma unroll
    for (int mt = 0; mt < 2; ++mt)
#pragma unroll
      for (int nt = 0; nt < 4; ++nt) {
        const int mb = m0 + wr * 32 + mt * 16 + g * 4;
        const int col = wc * 64 + nt * 16 + r16;
#pragma unroll
        for (int r = 0; r < 4; ++r)
          dst[(size_t)(mb + r) * H + col] = (f16)acc[mt][nt][r];
      }
  } else {
    const int b = m0 >> 11;
    const int tb0 = m0 & 2047;
    f16* vbase = vt + (size_t)b * H * T;
#pragma unroll
    for (int mt = 0; mt < 2; ++mt)
#pragma unroll
      for (int nt = 0; nt < 4; ++nt) {
        const int tib = tb0 + wr * 32 + mt * 16 + g * 4;
        const int h = wc * 64 + nt * 16 + r16;
        f16x4 pk;
#pragma unroll
        for (int r = 0; r < 4; ++r) pk[r] = (f16)acc[mt][nt][r];
        *(f16x4*)&vbase[(size_t)h * T + tib] = pk;
      }
  }
}

// ---------------------------------------------------------------------------
// Kernel 2: causal flash attention, fp16, block-level s-parity split.
// (unchanged: 512 blocks, XCD-pinned batch, LPT order, 64 q-rows,
//  K/V^T fp16 double-buffered LDS, XOR swizzle, 1-term fp16 QK^T, fp16 P.)
// ---------------------------------------------------------------------------
__global__ __launch_bounds__(256, 2) void attn_kernel(const f16* __restrict__ qp,
                                                      const f16* __restrict__ kp,
                                                      const f16* __restrict__ vp,
                                                      float* __restrict__ out,
                                                      f16* __restrict__ oS,
                                                      float* __restrict__ MLs) {
  __shared__ __align__(16) f16 KS[2][64 * 128];   // [s][h], chunk-swizzled
  __shared__ __align__(16) f16 VS[2][128 * 64];   // [h][s], chunk-swizzled
  __shared__ __align__(16) f16 Pl[4][16][72];     // per-wave P [q][s], padded

  const int tid = threadIdx.x, lane = tid & 63, wave = tid >> 6;
  const int g = lane >> 4, q15 = lane & 15;
  const int x7 = q15 & 7;
  const int bb = blockIdx.x;
  const int b = bb & 7;                 // block->XCD round-robin: pins batch L2
  const int t2 = bb >> 3;               // 0..63
  const int qt = 31 - (t2 >> 1);        // heavy tasks dispatch first (LPT)
  const int par = t2 & 1;
  const int q0 = qt * 64;
  const int qrow = q0 + wave * 16 + q15;
  const int task = b * 32 + qt;

  const f16* qb = qp + (size_t)b * T * H;
  const f16* kb = kp + (size_t)b * T * H;
  const f16* vb = vp + (size_t)b * H * T;

  int koff[4], voff[4], lo[4];
#pragma unroll
  for (int i = 0; i < 4; ++i) {
    const int u = wave * 4 + i;
    const int rK = u * 4 + (lane >> 4);
    koff[i] = rK * H + (((lane & 15) ^ (rK & 7)) << 3);
    const int hV = u * 8 + (lane >> 3);
    voff[i] = hV * T + (((lane & 7) ^ (hV & 7)) << 3);
    lo[i] = u * 512 + lane * 8;
  }

  const int n = (qt >= par) ? ((qt - par) >> 1) + 1 : 0;   // my tile count

  f16x8 qf[4];
#pragma unroll
  for (int k4 = 0; k4 < 4; ++k4)
    qf[k4] = *(const f16x8*)&qb[(size_t)qrow * H + k4 * 32 + g * 8];

  f32x4 o[8] = {};
  float mrun = -1e30f, lrun = 0.f;

  f16x8 rk[4], rv[4];
#define LOADT(S0)                                                   \
  _Pragma("unroll")                                                 \
  for (int i = 0; i < 4; ++i) {                                     \
    rk[i] = *(const f16x8*)&kb[(size_t)(S0) * H + koff[i]];         \
    rv[i] = *(const f16x8*)&vb[(size_t)(S0) + voff[i]];             \
  }
#define WRITET(BUF)                                                 \
  _Pragma("unroll")                                                 \
  for (int i = 0; i < 4; ++i) {                                     \
    *(f16x8*)&KS[BUF][lo[i]] = rk[i];                               \
    *(f16x8*)&VS[BUF][lo[i]] = rv[i];                               \
  }

  if (n > 0) {
    LOADT(par * 64);
    WRITET(0);
    if (n > 1) LOADT(par * 64 + 128);

    for (int k = 0; k < n; ++k) {
      const int s0 = par * 64 + k * 128;
      const int cur = k & 1;
      __syncthreads();  // WRITET(cur) by all waves complete

      f32x4 sacc[4] = {};
#pragma unroll
      for (int mt = 0; mt < 4; ++mt) {
        const int row = mt * 16 + q15;
#pragma unroll
        for (int k4 = 0; k4 < 4; ++k4) {
          const int pch = (k4 * 4 + g) ^ (row & 7);
          const f16x8 kf = *(const f16x8*)&KS[cur][row * 128 + pch * 8];
          sacc[mt] = MFMA_FP(kf, qf[k4], sacc[mt]);
        }
      }
      if (k == n - 1) {
#pragma unroll
        for (int mt = 0; mt < 4; ++mt)
#pragma unroll
          for (int r = 0; r < 4; ++r)
            if (s0 + mt * 16 + g * 4 + r > qrow) sacc[mt][r] = -1e30f;
      }
      float tmax = -1e30f;
#pragma unroll
      for (int mt = 0; mt < 4; ++mt)
#pragma unroll
        for (int r = 0; r < 4; ++r) tmax = fmaxf(tmax, sacc[mt][r]);
      tmax = fmaxf(tmax, __shfl_xor(tmax, 16));
      tmax = fmaxf(tmax, __shfl_xor(tmax, 32));
      const float mnew = fmaxf(mrun, tmax);
      const float alpha = __expf(mrun - mnew);
      float lt = 0.f;
#pragma unroll
      for (int mt = 0; mt < 4; ++mt) {
        f16x4 pk;
#pragma unroll
        for (int r = 0; r < 4; ++r) {
          const float p = __expf(sacc[mt][r] - mnew);
          lt += p;
          pk[r] = (f16)p;
        }
        *(f16x4*)&Pl[wave][q15][mt * 16 + g * 4] = pk;
      }
      lt += __shfl_xor(lt, 16);
      lt += __shfl_xor(lt, 32);
      lrun = lrun * alpha + lt;
      mrun = mnew;
#pragma unroll
      for (int i = 0; i < 8; ++i) o[i] *= alpha;
      const f16x8 pf0 = *(const f16x8*)&Pl[wave][q15][g * 8];
      const f16x8 pf1 = *(const f16x8*)&Pl[wave][q15][32 + g * 8];
#pragma unroll
      for (int mt = 0; mt < 8; ++mt) {
        const int h = mt * 16 + q15;
        const f16x8 vf0 = *(const f16x8*)&VS[cur][h * 64 + ((g ^ x7) << 3)];
        o[mt] = MFMA_FP(vf0, pf0, o[mt]);
        const f16x8 vf1 = *(const f16x8*)&VS[cur][h * 64 + (((4 + g) ^ x7) << 3)];
        o[mt] = MFMA_FP(vf1, pf1, o[mt]);
      }

      if (k + 1 < n) {
        WRITET(cur ^ 1);
        if (k + 2 < n) LOADT(par * 64 + (k + 2) * 128);
      }
    }
  }
#undef LOADT
#undef WRITET

  const float inv = (lrun > 0.f) ? 1.0f / lrun : 0.f;
  if (lane < 16) {
    MLs[((size_t)(task * 2 + par) * 64 + wave * 16 + lane) * 2 + 0] = mrun;
    MLs[((size_t)(task * 2 + par) * 64 + wave * 16 + lane) * 2 + 1] = lrun;
  }
  if (par == 0) {
    float* ob = out + ((size_t)b * T + qrow) * H;
#pragma unroll
    for (int mt = 0; mt < 8; ++mt) {
      f32x4 pk;
#pragma unroll
      for (int r = 0; r < 4; ++r) pk[r] = o[mt][r] * inv;
      *(f32x4*)&ob[mt * 16 + g * 4] = pk;
    }
  } else {
    f16* sb = oS + ((size_t)task * 64 + wave * 16 + q15) * 128;
#pragma unroll
    for (int mt = 0; mt < 8; ++mt) {
      f16x4 pk;
#pragma unroll
      for (int r = 0; r < 4; ++r) pk[r] = (f16)(o[mt][r] * inv);
      *(f16x4*)&sb[mt * 16 + g * 4] = pk;
    }
  }
}

// ---------------------------------------------------------------------------
// Kernel 3: combine the two parity partials per task (flash merge), in-place.
// ---------------------------------------------------------------------------
__global__ __launch_bounds__(256) void combine_kernel(float* __restrict__ out,
                                                      const f16* __restrict__ oS,
                                                      const float* __restrict__ MLs) {
  const int task = blockIdx.x;           // b*32 + qt
  const int b = task >> 5, qt = task & 31;
  const int tid = threadIdx.x;
  const int row = tid >> 2;
  const int cb = (tid & 3) * 32;
  const float m0 = MLs[((size_t)(task * 2 + 0) * 64 + row) * 2 + 0];
  const float l0 = MLs[((size_t)(task * 2 + 0) * 64 + row) * 2 + 1];
  const float m1 = MLs[((size_t)(task * 2 + 1) * 64 + row) * 2 + 0];
  const float l1 = MLs[((size_t)(task * 2 + 1) * 64 + row) * 2 + 1];
  const float Mg = fmaxf(m0, m1);
  const float w0 = l0 * __expf(m0 - Mg);
  const float w1 = l1 * __expf(m1 - Mg);
  const float inv = 1.0f / (w0 + w1);
  float* orow = out + ((size_t)b * T + qt * 64 + row) * H + cb;
  const f16* srow = oS + ((size_t)task * 64 + row) * 128 + cb;
#pragma unroll
  for (int c = 0; c < 32; c += 8) {
    const f16x8 o1 = *(const f16x8*)&srow[c];
    f32x4 a0 = *(const f32x4*)&orow[c];
    f32x4 a1 = *(const f32x4*)&orow[c + 4];
    f32x4 r0, r1;
#pragma unroll
    for (int r = 0; r < 4; ++r) {
      r0[r] = (w0 * a0[r] + w1 * (float)o1[r]) * inv;
      r1[r] = (w0 * a1[r] + w1 * (float)o1[4 + r]) * inv;
    }
    *(f32x4*)&orow[c] = r0;
    *(f32x4*)&orow[c + 4] = r1;
  }
}

// ---------------------------------------------------------------------------
extern "C" void kernel_launch(void* const* d_in, const int* in_sizes, int n_in,
                              void* d_out, int out_size, void* d_ws, size_t ws_size,
                              hipStream_t stream) {
  const float* x  = (const float*)d_in[0];   // fp32 inputs per reference
  const float* Wq = (const float*)d_in[1];
  const float* Wk = (const float*)d_in[2];
  const float* Wv = (const float*)d_in[3];
  float* out = (float*)d_out;                // fp32 output

  f16*  wt  = (f16*)d_ws;                             // 3*H*C fp16 (384 x C)
  f16*  qf  = wt + (size_t)3 * H * C;                 // M*H fp16
  f16*  kf  = qf + (size_t)M * H;                     // M*H fp16
  f16*  vf  = kf + (size_t)M * H;                     // M*H fp16 [b][h][t]
  f16*  oS  = vf + (size_t)M * H;                     // 256*64*128 fp16
  float* MLs = (float*)(oS + (size_t)256 * 64 * 128); // 256*2*64*2 f32

  kwt<<<dim3(C / 32, H / 32, 3), 256, 0, stream>>>(Wq, Wk, Wv, wt);
  proj_kernel<<<dim3(M / 64, 3), 256, 0, stream>>>(x, wt, qf, kf, vf);
  attn_kernel<<<512, 256, 0, stream>>>(qf, kf, vf, out, oS, MLs);
  combine_kernel<<<256, 256, 0, stream>>>(out, oS, MLs);
}

// Round 15
// 67.405 us; speedup vs baseline: 1.9129x; 1.9129x over previous
//
#include <hip/hip_runtime.h>

typedef __bf16 bf16;
typedef _Float16 f16;
typedef f16 f16x4 __attribute__((ext_vector_type(4)));
typedef f16 f16x8 __attribute__((ext_vector_type(8)));
typedef float f32x4 __attribute__((ext_vector_type(4)));

#define MFMA_FP(a, b, c) __builtin_amdgcn_mfma_f32_16x16x32_f16((a), (b), (c), 0, 0, 0)

static constexpr int Bn = 8, T = 2048, C = 1024, H = 128;
static constexpr int M = Bn * T; // 16384

// direct global->LDS, 16B per lane (lds dest is wave-uniform base + lane*16)
__device__ __forceinline__ void gll16(const void* g, void* l) {
  __builtin_amdgcn_global_load_lds(
      (const __attribute__((address_space(1))) unsigned int*)g,
      (__attribute__((address_space(3))) unsigned int*)l, 16, 0, 0);
}

// ---------------------------------------------------------------------------
// Kernel 0: transpose  W[C][H] fp32 -> wt [3][H][C] fp16 (stacked 384 x C)
// ---------------------------------------------------------------------------
__global__ __launch_bounds__(256) void kwt(const float* __restrict__ Wq,
                                           const float* __restrict__ Wk,
                                           const float* __restrict__ Wv,
                                           f16* __restrict__ wt) {
  __shared__ float tl[32][33];
  const int w = blockIdx.z;
  const float* src = (w == 0) ? Wq : (w == 1) ? Wk : Wv;
  f16* dh = wt + (size_t)w * H * C;
  const int k0 = blockIdx.x * 32, n0 = blockIdx.y * 32;
  const int tx = threadIdx.x & 31, ty = threadIdx.x >> 5; // 32 x 8
  for (int i = ty; i < 32; i += 8) tl[i][tx] = src[(size_t)(k0 + i) * H + n0 + tx];
  __syncthreads();
  for (int i = ty; i < 32; i += 8)
    dh[(size_t)(n0 + i) * C + k0 + tx] = (f16)tl[tx][i];
}

// ---------------------------------------------------------------------------
// Kernel 1: QKV projection — double-buffered at 3 blocks/CU (the untested
// cell of the measured ladder: R9's residency + R10's load-hiding rhythm).
// grid (M/64, 3) = 768 blocks = 3/CU (LDS 48KB, VGPR capped by (256,3)).
// Tile 64m x 128n, BK=64, 4 waves (2x2); wave = 32m x 64n (mt=2, nt=4).
//   As[2] = x tile cvt->fp16 [64][64] (8KB each), REG-staged: f32 loads
//           issued BEFORE the B glls (older in vmem queue) so WRITEA's
//           implicit wait covers only A; B glls fly through the compute.
//   Bs[2] = wt tile fp16 [128][64] (16KB each) via global_load_lds w16.
// ONE barrier per step: barrier -> issue(next->other buf) -> compute(cur)
// -> WRITEA(other).  Barrier drains prev-iter B glls after a full compute
// phase of hiding.  XOR chunk-swizzle (phys16B = logical ^ (row&7)); frag
// reads 2-way max (free).
// ---------------------------------------------------------------------------
__global__ __launch_bounds__(256, 3) void proj_kernel(const float* __restrict__ x,
                                                      const f16* __restrict__ wt,
                                                      f16* __restrict__ qo,
                                                      f16* __restrict__ ko,
                                                      f16* __restrict__ vt) {
  __shared__ __align__(16) f16 As[2][64 * 64];    // [m][k] swizzled, 8KB each
  __shared__ __align__(16) f16 Bs[2][128 * 64];   // [n][k] swizzled, 16KB each
  const int tid = threadIdx.x;
  const int lane = tid & 63, g = lane >> 4, r16 = lane & 15;
  const int wave = tid >> 6, wr = wave >> 1, wc = wave & 1;
  const int m0 = blockIdx.x * 64;
  const int which = blockIdx.y;
  const f16* wh = wt + (size_t)which * H * C;

  // A: 8 units of 1KB (8 rows x 128B f16); wave stages units wave*2+i.
  //   lane l, unit u: row rA = u*8 + (l>>3); src f32 chunk = (l&7)^(rA&7),
  //   i.e. 8 f32 at asrc (2x f32x4), cvt to f16x8, ds_write at aldw.
  // B: 16 units of 1KB (8 rows x 128B); wave stages units wave*4+i via gll.
  int asrc[2], aldw[2], bsrc[4], bldu[4];
#pragma unroll
  for (int i = 0; i < 2; ++i) {
    const int u = wave * 2 + i;
    const int rA = u * 8 + (lane >> 3);
    asrc[i] = (m0 + rA) * C + (((lane & 7) ^ (rA & 7)) << 3);   // f32 elems
    aldw[i] = rA * 64 + (lane & 7) * 8;                          // f16 elems
  }
#pragma unroll
  for (int i = 0; i < 4; ++i) {
    const int u = wave * 4 + i;
    const int rb = u * 8 + (lane >> 3);
    bsrc[i] = rb * C + (((lane & 7) ^ (rb & 7)) << 3);           // f16 elems
    bldu[i] = u * 512;                                           // f16 elems
  }

  f32x4 acc[2][4] = {};
  f32x4 arg[2][2];   // A f32 regs in flight

#define LOADA(K0)                                                  \
  _Pragma("unroll")                                                \
  for (int i = 0; i < 2; ++i) {                                    \
    arg[i][0] = *(const f32x4*)&x[asrc[i] + (K0)];                 \
    arg[i][1] = *(const f32x4*)&x[asrc[i] + (K0) + 4];             \
  }
#define ISSUEB(K0, BUF)                                            \
  _Pragma("unroll")                                                \
  for (int i = 0; i < 4; ++i)                                      \
    gll16(&wh[bsrc[i] + (K0)], &Bs[BUF][bldu[i]]);
#define WRITEA(BUF)                                                \
  _Pragma("unroll")                                                \
  for (int i = 0; i < 2; ++i) {                                    \
    f16x8 av;                                                      \
    _Pragma("unroll")                                              \
    for (int j = 0; j < 4; ++j) {                                  \
      av[j] = (f16)arg[i][0][j];                                   \
      av[4 + j] = (f16)arg[i][1][j];                               \
    }                                                              \
    *(f16x8*)&As[BUF][aldw[i]] = av;                               \
  }

  // prologue: stage tile 0 (A loads first -> WRITEA waits only A)
  LOADA(0);
  ISSUEB(0, 0);
  WRITEA(0);

  for (int k = 0; k < 16; ++k) {
    const int cur = k & 1;
    const int k0 = k * 64;
    __syncthreads();   // drains vm+lgkm: buf[cur] ready; prev reads of cur^1 done
    if (k < 15) {
      LOADA(k0 + 64);              // A loads (older) ...
      ISSUEB(k0 + 64, cur ^ 1);    // ... B glls hide under this compute
    }
#pragma unroll
    for (int kb = 0; kb < 2; ++kb) {
      f16x8 af[2], bf[4];
#pragma unroll
      for (int mt = 0; mt < 2; ++mt) {
        const int r = wr * 32 + mt * 16 + r16;
        const int phys = (kb * 4 + g) ^ (r & 7);
        af[mt] = *(const f16x8*)&As[cur][r * 64 + phys * 8];
      }
#pragma unroll
      for (int nt = 0; nt < 4; ++nt) {
        const int r = wc * 64 + nt * 16 + r16;
        const int phys = (kb * 4 + g) ^ (r & 7);
        bf[nt] = *(const f16x8*)&Bs[cur][r * 64 + phys * 8];
      }
#pragma unroll
      for (int mt = 0; mt < 2; ++mt)
#pragma unroll
        for (int nt = 0; nt < 4; ++nt)
          acc[mt][nt] = MFMA_FP(af[mt], bf[nt], acc[mt][nt]);
    }
    if (k < 15) WRITEA(cur ^ 1);   // waits A loads only; B still flying
  }
#undef LOADA
#undef ISSUEB
#undef WRITEA

  // epilogue.  C/D frag: col = lane&15, row = (lane>>4)*4 + reg  [m89]
  if (which < 2) {
    f16* dst = which ? ko : qo;
#pragma unroll
    for (int mt = 0; mt < 2; ++mt)
#pragma unroll
      for (int nt = 0; nt < 4; ++nt) {
        const int mb = m0 + wr * 32 + mt * 16 + g * 4;
        const int col = wc * 64 + nt * 16 + r16;
#pragma unroll
        for (int r = 0; r < 4; ++r)
          dst[(size_t)(mb + r) * H + col] = (f16)acc[mt][nt][r];
      }
  } else {
    const int b = m0 >> 11;
    const int tb0 = m0 & 2047;
    f16* vbase = vt + (size_t)b * H * T;
#pragma unroll
    for (int mt = 0; mt < 2; ++mt)
#pragma unroll
      for (int nt = 0; nt < 4; ++nt) {
        const int tib = tb0 + wr * 32 + mt * 16 + g * 4;
        const int h = wc * 64 + nt * 16 + r16;
        f16x4 pk;
#pragma unroll
        for (int r = 0; r < 4; ++r) pk[r] = (f16)acc[mt][nt][r];
        *(f16x4*)&vbase[(size_t)h * T + tib] = pk;
      }
  }
}

// ---------------------------------------------------------------------------
// Kernel 2: causal flash attention, fp16, block-level s-parity split.
// (structure unchanged; adds defer-max (T13): skip O-rescale while the tile
//  max stays within +8 of the running max — P bounded by e^8 < fp16 max.)
// ---------------------------------------------------------------------------
__global__ __launch_bounds__(256, 2) void attn_kernel(const f16* __restrict__ qp,
                                                      const f16* __restrict__ kp,
                                                      const f16* __restrict__ vp,
                                                      float* __restrict__ out,
                                                      f16* __restrict__ oS,
                                                      float* __restrict__ MLs) {
  __shared__ __align__(16) f16 KS[2][64 * 128];   // [s][h], chunk-swizzled
  __shared__ __align__(16) f16 VS[2][128 * 64];   // [h][s], chunk-swizzled
  __shared__ __align__(16) f16 Pl[4][16][72];     // per-wave P [q][s], padded

  const int tid = threadIdx.x, lane = tid & 63, wave = tid >> 6;
  const int g = lane >> 4, q15 = lane & 15;
  const int x7 = q15 & 7;
  const int bb = blockIdx.x;
  const int b = bb & 7;                 // block->XCD round-robin: pins batch L2
  const int t2 = bb >> 3;               // 0..63
  const int qt = 31 - (t2 >> 1);        // heavy tasks dispatch first (LPT)
  const int par = t2 & 1;
  const int q0 = qt * 64;
  const int qrow = q0 + wave * 16 + q15;
  const int task = b * 32 + qt;

  const f16* qb = qp + (size_t)b * T * H;
  const f16* kb = kp + (size_t)b * T * H;
  const f16* vb = vp + (size_t)b * H * T;

  int koff[4], voff[4], lo[4];
#pragma unroll
  for (int i = 0; i < 4; ++i) {
    const int u = wave * 4 + i;
    const int rK = u * 4 + (lane >> 4);
    koff[i] = rK * H + (((lane & 15) ^ (rK & 7)) << 3);
    const int hV = u * 8 + (lane >> 3);
    voff[i] = hV * T + (((lane & 7) ^ (hV & 7)) << 3);
    lo[i] = u * 512 + lane * 8;
  }

  const int n = (qt >= par) ? ((qt - par) >> 1) + 1 : 0;   // my tile count

  f16x8 qf[4];
#pragma unroll
  for (int k4 = 0; k4 < 4; ++k4)
    qf[k4] = *(const f16x8*)&qb[(size_t)qrow * H + k4 * 32 + g * 8];

  f32x4 o[8] = {};
  float mrun = -1e30f, lrun = 0.f;

  f16x8 rk[4], rv[4];
#define LOADT(S0)                                                   \
  _Pragma("unroll")                                                 \
  for (int i = 0; i < 4; ++i) {                                     \
    rk[i] = *(const f16x8*)&kb[(size_t)(S0) * H + koff[i]];         \
    rv[i] = *(const f16x8*)&vb[(size_t)(S0) + voff[i]];             \
  }
#define WRITET(BUF)                                                 \
  _Pragma("unroll")                                                 \
  for (int i = 0; i < 4; ++i) {                                     \
    *(f16x8*)&KS[BUF][lo[i]] = rk[i];                               \
    *(f16x8*)&VS[BUF][lo[i]] = rv[i];                               \
  }

  if (n > 0) {
    LOADT(par * 64);
    WRITET(0);
    if (n > 1) LOADT(par * 64 + 128);

    for (int k = 0; k < n; ++k) {
      const int s0 = par * 64 + k * 128;
      const int cur = k & 1;
      __syncthreads();  // WRITET(cur) by all waves complete

      f32x4 sacc[4] = {};
#pragma unroll
      for (int mt = 0; mt < 4; ++mt) {
        const int row = mt * 16 + q15;
#pragma unroll
        for (int k4 = 0; k4 < 4; ++k4) {
          const int pch = (k4 * 4 + g) ^ (row & 7);
          const f16x8 kf = *(const f16x8*)&KS[cur][row * 128 + pch * 8];
          sacc[mt] = MFMA_FP(kf, qf[k4], sacc[mt]);
        }
      }
      if (k == n - 1) {
#pragma unroll
        for (int mt = 0; mt < 4; ++mt)
#pragma unroll
          for (int r = 0; r < 4; ++r)
            if (s0 + mt * 16 + g * 4 + r > qrow) sacc[mt][r] = -1e30f;
      }
      float tmax = -1e30f;
#pragma unroll
      for (int mt = 0; mt < 4; ++mt)
#pragma unroll
        for (int r = 0; r < 4; ++r) tmax = fmaxf(tmax, sacc[mt][r]);
      tmax = fmaxf(tmax, __shfl_xor(tmax, 16));
      tmax = fmaxf(tmax, __shfl_xor(tmax, 32));
      // defer-max (T13): only rescale when some row exceeds mrun+8;
      // otherwise P = exp(s - mrun) <= e^8 = 2981 fits fp16 comfortably.
      if (!__all(tmax <= mrun + 8.f)) {
        const float mnew = fmaxf(mrun, tmax);
        const float alpha = __expf(mrun - mnew);
        lrun *= alpha;
#pragma unroll
        for (int i = 0; i < 8; ++i) o[i] *= alpha;
        mrun = mnew;
      }
      float lt = 0.f;
#pragma unroll
      for (int mt = 0; mt < 4; ++mt) {
        f16x4 pk;
#pragma unroll
        for (int r = 0; r < 4; ++r) {
          const float p = __expf(sacc[mt][r] - mrun);
          lt += p;
          pk[r] = (f16)p;
        }
        *(f16x4*)&Pl[wave][q15][mt * 16 + g * 4] = pk;
      }
      lt += __shfl_xor(lt, 16);
      lt += __shfl_xor(lt, 32);
      lrun += lt;
      const f16x8 pf0 = *(const f16x8*)&Pl[wave][q15][g * 8];
      const f16x8 pf1 = *(const f16x8*)&Pl[wave][q15][32 + g * 8];
#pragma unroll
      for (int mt = 0; mt < 8; ++mt) {
        const int h = mt * 16 + q15;
        const f16x8 vf0 = *(const f16x8*)&VS[cur][h * 64 + ((g ^ x7) << 3)];
        o[mt] = MFMA_FP(vf0, pf0, o[mt]);
        const f16x8 vf1 = *(const f16x8*)&VS[cur][h * 64 + (((4 + g) ^ x7) << 3)];
        o[mt] = MFMA_FP(vf1, pf1, o[mt]);
      }

      if (k + 1 < n) {
        WRITET(cur ^ 1);
        if (k + 2 < n) LOADT(par * 64 + (k + 2) * 128);
      }
    }
  }
#undef LOADT
#undef WRITET

  const float inv = (lrun > 0.f) ? 1.0f / lrun : 0.f;
  if (lane < 16) {
    MLs[((size_t)(task * 2 + par) * 64 + wave * 16 + lane) * 2 + 0] = mrun;
    MLs[((size_t)(task * 2 + par) * 64 + wave * 16 + lane) * 2 + 1] = lrun;
  }
  if (par == 0) {
    float* ob = out + ((size_t)b * T + qrow) * H;
#pragma unroll
    for (int mt = 0; mt < 8; ++mt) {
      f32x4 pk;
#pragma unroll
      for (int r = 0; r < 4; ++r) pk[r] = o[mt][r] * inv;
      *(f32x4*)&ob[mt * 16 + g * 4] = pk;
    }
  } else {
    f16* sb = oS + ((size_t)task * 64 + wave * 16 + q15) * 128;
#pragma unroll
    for (int mt = 0; mt < 8; ++mt) {
      f16x4 pk;
#pragma unroll
      for (int r = 0; r < 4; ++r) pk[r] = (f16)(o[mt][r] * inv);
      *(f16x4*)&sb[mt * 16 + g * 4] = pk;
    }
  }
}

// ---------------------------------------------------------------------------
// Kernel 3: combine the two parity partials per task (flash merge), in-place.
// ---------------------------------------------------------------------------
__global__ __launch_bounds__(256) void combine_kernel(float* __restrict__ out,
                                                      const f16* __restrict__ oS,
                                                      const float* __restrict__ MLs) {
  const int task = blockIdx.x;           // b*32 + qt
  const int b = task >> 5, qt = task & 31;
  const int tid = threadIdx.x;
  const int row = tid >> 2;
  const int cb = (tid & 3) * 32;
  const float m0 = MLs[((size_t)(task * 2 + 0) * 64 + row) * 2 + 0];
  const float l0 = MLs[((size_t)(task * 2 + 0) * 64 + row) * 2 + 1];
  const float m1 = MLs[((size_t)(task * 2 + 1) * 64 + row) * 2 + 0];
  const float l1 = MLs[((size_t)(task * 2 + 1) * 64 + row) * 2 + 1];
  const float Mg = fmaxf(m0, m1);
  const float w0 = l0 * __expf(m0 - Mg);
  const float w1 = l1 * __expf(m1 - Mg);
  const float inv = 1.0f / (w0 + w1);
  float* orow = out + ((size_t)b * T + qt * 64 + row) * H + cb;
  const f16* srow = oS + ((size_t)task * 64 + row) * 128 + cb;
#pragma unroll
  for (int c = 0; c < 32; c += 8) {
    const f16x8 o1 = *(const f16x8*)&srow[c];
    f32x4 a0 = *(const f32x4*)&orow[c];
    f32x4 a1 = *(const f32x4*)&orow[c + 4];
    f32x4 r0, r1;
#pragma unroll
    for (int r = 0; r < 4; ++r) {
      r0[r] = (w0 * a0[r] + w1 * (float)o1[r]) * inv;
      r1[r] = (w0 * a1[r] + w1 * (float)o1[4 + r]) * inv;
    }
    *(f32x4*)&orow[c] = r0;
    *(f32x4*)&orow[c + 4] = r1;
  }
}

// ---------------------------------------------------------------------------
extern "C" void kernel_launch(void* const* d_in, const int* in_sizes, int n_in,
                              void* d_out, int out_size, void* d_ws, size_t ws_size,
                              hipStream_t stream) {
  const float* x  = (const float*)d_in[0];   // fp32 inputs per reference
  const float* Wq = (const float*)d_in[1];
  const float* Wk = (const float*)d_in[2];
  const float* Wv = (const float*)d_in[3];
  float* out = (float*)d_out;                // fp32 output

  f16*  wt  = (f16*)d_ws;                             // 3*H*C fp16 (384 x C)
  f16*  qf  = wt + (size_t)3 * H * C;                 // M*H fp16
  f16*  kf  = qf + (size_t)M * H;                     // M*H fp16
  f16*  vf  = kf + (size_t)M * H;                     // M*H fp16 [b][h][t]
  f16*  oS  = vf + (size_t)M * H;                     // 256*64*128 fp16
  float* MLs = (float*)(oS + (size_t)256 * 64 * 128); // 256*2*64*2 f32

  kwt<<<dim3(C / 32, H / 32, 3), 256, 0, stream>>>(Wq, Wk, Wv, wt);
  proj_kernel<<<dim3(M / 64, 3), 256, 0, stream>>>(x, wt, qf, kf, vf);
  attn_kernel<<<512, 256, 0, stream>>>(qf, kf, vf, out, oS, MLs);
  combine_kernel<<<256, 256, 0, stream>>>(out, oS, MLs);
}

// Round 16
// 65.495 us; speedup vs baseline: 1.9687x; 1.0292x over previous
//
#include <hip/hip_runtime.h>

typedef __bf16 bf16;
typedef _Float16 f16;
typedef f16 f16x4 __attribute__((ext_vector_type(4)));
typedef f16 f16x8 __attribute__((ext_vector_type(8)));
typedef float f32x4 __attribute__((ext_vector_type(4)));

#define MFMA_FP(a, b, c) __builtin_amdgcn_mfma_f32_16x16x32_f16((a), (b), (c), 0, 0, 0)

static constexpr int Bn = 8, T = 2048, C = 1024, H = 128;
static constexpr int M = Bn * T; // 16384

// direct global->LDS, 16B per lane (lds dest is wave-uniform base + lane*16)
__device__ __forceinline__ void gll16(const void* g, void* l) {
  __builtin_amdgcn_global_load_lds(
      (const __attribute__((address_space(1))) unsigned int*)g,
      (__attribute__((address_space(3))) unsigned int*)l, 16, 0, 0);
}

// ---------------------------------------------------------------------------
// Kernel 0: transpose  W[C][H] fp32 -> wt [3][H][C] fp16
// ---------------------------------------------------------------------------
__global__ __launch_bounds__(256) void kwt(const float* __restrict__ Wq,
                                           const float* __restrict__ Wk,
                                           const float* __restrict__ Wv,
                                           f16* __restrict__ wt) {
  __shared__ float tl[32][33];
  const int w = blockIdx.z;
  const float* src = (w == 0) ? Wq : (w == 1) ? Wk : Wv;
  f16* dh = wt + (size_t)w * H * C;
  const int k0 = blockIdx.x * 32, n0 = blockIdx.y * 32;
  const int tx = threadIdx.x & 31, ty = threadIdx.x >> 5; // 32 x 8
  for (int i = ty; i < 32; i += 8) tl[i][tx] = src[(size_t)(k0 + i) * H + n0 + tx];
  __syncthreads();
  for (int i = ty; i < 32; i += 8)
    dh[(size_t)(n0 + i) * C + k0 + tx] = (f16)tl[tx][i];
}

// ---------------------------------------------------------------------------
// Kernel 1: QKV projection — EXACT R9 configuration (best measured: ~35us).
// Single-buffer, global_load_lds width-16 for BOTH operands, 2 barriers/step,
// grid (M/64, 3) = 768 blocks = 3/CU.  Cross-block TLP (12 waves/CU) covers
// the per-step vmcnt drain; every deeper pipeline variant measured worse.
//   As = x tile fp32 [64][64] (16KB), cvt->fp16 at frag read;
//   Bs = wt tile fp16 [128][64] (16KB).
// LDS dest linear; SOURCE chunk pre-XOR'd (logical = phys ^ (row&7)) so
// frag reads with phys = logical ^ (row&7) are conflict-free (verified 0).
// y==0 -> q fp16 [t][h]; y==1 -> k fp16; y==2 -> v fp16 transposed [b][h][t].
// ---------------------------------------------------------------------------
__global__ __launch_bounds__(256) void proj_kernel(const float* __restrict__ x,
                                                   const f16* __restrict__ wt,
                                                   f16* __restrict__ qo,
                                                   f16* __restrict__ ko,
                                                   f16* __restrict__ vt) {
  __shared__ __align__(16) float As[64 * 64];   // [m][k] f32, swizzled, 16KB
  __shared__ __align__(16) f16  Bs[128 * 64];   // [n][k] f16, swizzled, 16KB
  const int tid = threadIdx.x;
  const int lane = tid & 63, g = lane >> 4, r16 = lane & 15;
  const int wave = tid >> 6, wr = wave >> 1, wc = wave & 1;
  const int m0 = blockIdx.x * 64;
  const int which = blockIdx.y;
  const f16* wh = wt + (size_t)which * H * C;

  // A: 64 rows x 256B = 16 units of 1KB (4 rows each); wave stages 4 units.
  //   lane l in unit u: LDS chunk = l (linear); row = u*4 + (l>>4);
  //   source f32 col-chunk = (l&15) ^ (row&7)  (16B = 4 f32 per chunk).
  // B: 128 rows x 128B = 16 units (8 rows each); source chunk = (l&7)^(row&7).
  int asrc[4], bsrc[4];      // source element offsets (excl. k0)
  int aldu[4], bldu[4];      // LDS unit base (element index), wave-uniform
#pragma unroll
  for (int i = 0; i < 4; ++i) {
    const int u = wave * 4 + i;
    const int ra = u * 4 + (lane >> 4);
    asrc[i] = (m0 + ra) * C + (((lane & 15) ^ (ra & 7)) << 2);
    aldu[i] = u * 256;                      // 256 f32 per unit
    const int rb = u * 8 + (lane >> 3);
    bsrc[i] = rb * C + (((lane & 7) ^ (rb & 7)) << 3);
    bldu[i] = u * 512;                      // 512 f16 per unit
  }

  f32x4 acc[2][4] = {};

#define ISSUE(K0)                                                  \
  _Pragma("unroll")                                                \
  for (int i = 0; i < 4; ++i) {                                    \
    gll16(&x[asrc[i] + (K0)], &As[aldu[i]]);                       \
    gll16(&wh[bsrc[i] + (K0)], &Bs[bldu[i]]);                      \
  }

  ISSUE(0);
  for (int k0 = 0; k0 < C; k0 += 64) {
    __syncthreads();   // vmcnt drained before barrier -> tile ready
#pragma unroll
    for (int kb = 0; kb < 2; ++kb) {
      f16x8 af[2], bf[4];
#pragma unroll
      for (int mt = 0; mt < 2; ++mt) {
        const int r = wr * 32 + mt * 16 + r16;
        const int s = r & 7;
        const f32x4 a0 = *(const f32x4*)&As[r * 64 + (((kb * 8 + g * 2) ^ s) << 2)];
        const f32x4 a1 = *(const f32x4*)&As[r * 64 + (((kb * 8 + g * 2 + 1) ^ s) << 2)];
#pragma unroll
        for (int j = 0; j < 4; ++j) { af[mt][j] = (f16)a0[j]; af[mt][4 + j] = (f16)a1[j]; }
      }
#pragma unroll
      for (int nt = 0; nt < 4; ++nt) {
        const int r = wc * 64 + nt * 16 + r16;
        const int phys = (kb * 4 + g) ^ (r & 7);
        bf[nt] = *(const f16x8*)&Bs[r * 64 + phys * 8];
      }
#pragma unroll
      for (int mt = 0; mt < 2; ++mt)
#pragma unroll
        for (int nt = 0; nt < 4; ++nt)
          acc[mt][nt] = MFMA_FP(af[mt], bf[nt], acc[mt][nt]);
    }
    __syncthreads();   // all reads done before next tile overwrites
    if (k0 + 64 < C) ISSUE(k0 + 64);
  }
#undef ISSUE

  // epilogue.  C/D frag: col = lane&15, row = (lane>>4)*4 + reg  [m89]
  if (which < 2) {
    f16* dst = which ? ko : qo;
#pragma unroll
    for (int mt = 0; mt < 2; ++mt)
#pragma unroll
      for (int nt = 0; nt < 4; ++nt) {
        const int mb = m0 + wr * 32 + mt * 16 + g * 4;
        const int col = wc * 64 + nt * 16 + r16;
#pragma unroll
        for (int r = 0; r < 4; ++r)
          dst[(size_t)(mb + r) * H + col] = (f16)acc[mt][nt][r];
      }
  } else {
    const int b = m0 >> 11;
    const int tb0 = m0 & 2047;
    f16* vbase = vt + (size_t)b * H * T;
#pragma unroll
    for (int mt = 0; mt < 2; ++mt)
#pragma unroll
      for (int nt = 0; nt < 4; ++nt) {
        const int tib = tb0 + wr * 32 + mt * 16 + g * 4;
        const int h = wc * 64 + nt * 16 + r16;
        f16x4 pk;
#pragma unroll
        for (int r = 0; r < 4; ++r) pk[r] = (f16)acc[mt][nt][r];
        *(f16x4*)&vbase[(size_t)h * T + tib] = pk;
      }
  }
}

// ---------------------------------------------------------------------------
// Kernel 2: causal flash attention, fp16, block-level s-parity split,
// with defer-max (T13): skip O-rescale while tile max <= mrun + 8.
// 512 blocks: b = bb&7 (XCD-pinned), qt = 31-(bb>>4) (LPT), par = (bb>>3)&1.
// ---------------------------------------------------------------------------
__global__ __launch_bounds__(256, 2) void attn_kernel(const f16* __restrict__ qp,
                                                      const f16* __restrict__ kp,
                                                      const f16* __restrict__ vp,
                                                      float* __restrict__ out,
                                                      f16* __restrict__ oS,
                                                      float* __restrict__ MLs) {
  __shared__ __align__(16) f16 KS[2][64 * 128];   // [s][h], chunk-swizzled
  __shared__ __align__(16) f16 VS[2][128 * 64];   // [h][s], chunk-swizzled
  __shared__ __align__(16) f16 Pl[4][16][72];     // per-wave P [q][s], padded

  const int tid = threadIdx.x, lane = tid & 63, wave = tid >> 6;
  const int g = lane >> 4, q15 = lane & 15;
  const int x7 = q15 & 7;
  const int bb = blockIdx.x;
  const int b = bb & 7;                 // block->XCD round-robin: pins batch L2
  const int t2 = bb >> 3;               // 0..63
  const int qt = 31 - (t2 >> 1);        // heavy tasks dispatch first (LPT)
  const int par = t2 & 1;
  const int q0 = qt * 64;
  const int qrow = q0 + wave * 16 + q15;
  const int task = b * 32 + qt;

  const f16* qb = qp + (size_t)b * T * H;
  const f16* kb = kp + (size_t)b * T * H;
  const f16* vb = vp + (size_t)b * H * T;

  int koff[4], voff[4], lo[4];
#pragma unroll
  for (int i = 0; i < 4; ++i) {
    const int u = wave * 4 + i;
    const int rK = u * 4 + (lane >> 4);
    koff[i] = rK * H + (((lane & 15) ^ (rK & 7)) << 3);
    const int hV = u * 8 + (lane >> 3);
    voff[i] = hV * T + (((lane & 7) ^ (hV & 7)) << 3);
    lo[i] = u * 512 + lane * 8;
  }

  const int n = (qt >= par) ? ((qt - par) >> 1) + 1 : 0;   // my tile count

  f16x8 qf[4];
#pragma unroll
  for (int k4 = 0; k4 < 4; ++k4)
    qf[k4] = *(const f16x8*)&qb[(size_t)qrow * H + k4 * 32 + g * 8];

  f32x4 o[8] = {};
  float mrun = -1e30f, lrun = 0.f;

  f16x8 rk[4], rv[4];
#define LOADT(S0)                                                   \
  _Pragma("unroll")                                                 \
  for (int i = 0; i < 4; ++i) {                                     \
    rk[i] = *(const f16x8*)&kb[(size_t)(S0) * H + koff[i]];         \
    rv[i] = *(const f16x8*)&vb[(size_t)(S0) + voff[i]];             \
  }
#define WRITET(BUF)                                                 \
  _Pragma("unroll")                                                 \
  for (int i = 0; i < 4; ++i) {                                     \
    *(f16x8*)&KS[BUF][lo[i]] = rk[i];                               \
    *(f16x8*)&VS[BUF][lo[i]] = rv[i];                               \
  }

  if (n > 0) {
    LOADT(par * 64);
    WRITET(0);
    if (n > 1) LOADT(par * 64 + 128);

    for (int k = 0; k < n; ++k) {
      const int s0 = par * 64 + k * 128;
      const int cur = k & 1;
      __syncthreads();  // WRITET(cur) by all waves complete

      f32x4 sacc[4] = {};
#pragma unroll
      for (int mt = 0; mt < 4; ++mt) {
        const int row = mt * 16 + q15;
#pragma unroll
        for (int k4 = 0; k4 < 4; ++k4) {
          const int pch = (k4 * 4 + g) ^ (row & 7);
          const f16x8 kf = *(const f16x8*)&KS[cur][row * 128 + pch * 8];
          sacc[mt] = MFMA_FP(kf, qf[k4], sacc[mt]);
        }
      }
      if (k == n - 1) {
#pragma unroll
        for (int mt = 0; mt < 4; ++mt)
#pragma unroll
          for (int r = 0; r < 4; ++r)
            if (s0 + mt * 16 + g * 4 + r > qrow) sacc[mt][r] = -1e30f;
      }
      float tmax = -1e30f;
#pragma unroll
      for (int mt = 0; mt < 4; ++mt)
#pragma unroll
        for (int r = 0; r < 4; ++r) tmax = fmaxf(tmax, sacc[mt][r]);
      tmax = fmaxf(tmax, __shfl_xor(tmax, 16));
      tmax = fmaxf(tmax, __shfl_xor(tmax, 32));
      // defer-max (T13): only rescale when some row exceeds mrun+8;
      // otherwise P = exp(s - mrun) <= e^8 = 2981 fits fp16 comfortably.
      if (!__all(tmax <= mrun + 8.f)) {
        const float mnew = fmaxf(mrun, tmax);
        const float alpha = __expf(mrun - mnew);
        lrun *= alpha;
#pragma unroll
        for (int i = 0; i < 8; ++i) o[i] *= alpha;
        mrun = mnew;
      }
      float lt = 0.f;
#pragma unroll
      for (int mt = 0; mt < 4; ++mt) {
        f16x4 pk;
#pragma unroll
        for (int r = 0; r < 4; ++r) {
          const float p = __expf(sacc[mt][r] - mrun);
          lt += p;
          pk[r] = (f16)p;
        }
        *(f16x4*)&Pl[wave][q15][mt * 16 + g * 4] = pk;
      }
      lt += __shfl_xor(lt, 16);
      lt += __shfl_xor(lt, 32);
      lrun += lt;
      const f16x8 pf0 = *(const f16x8*)&Pl[wave][q15][g * 8];
      const f16x8 pf1 = *(const f16x8*)&Pl[wave][q15][32 + g * 8];
#pragma unroll
      for (int mt = 0; mt < 8; ++mt) {
        const int h = mt * 16 + q15;
        const f16x8 vf0 = *(const f16x8*)&VS[cur][h * 64 + ((g ^ x7) << 3)];
        o[mt] = MFMA_FP(vf0, pf0, o[mt]);
        const f16x8 vf1 = *(const f16x8*)&VS[cur][h * 64 + (((4 + g) ^ x7) << 3)];
        o[mt] = MFMA_FP(vf1, pf1, o[mt]);
      }

      if (k + 1 < n) {
        WRITET(cur ^ 1);
        if (k + 2 < n) LOADT(par * 64 + (k + 2) * 128);
      }
    }
  }
#undef LOADT
#undef WRITET

  const float inv = (lrun > 0.f) ? 1.0f / lrun : 0.f;
  if (lane < 16) {
    MLs[((size_t)(task * 2 + par) * 64 + wave * 16 + lane) * 2 + 0] = mrun;
    MLs[((size_t)(task * 2 + par) * 64 + wave * 16 + lane) * 2 + 1] = lrun;
  }
  if (par == 0) {
    float* ob = out + ((size_t)b * T + qrow) * H;
#pragma unroll
    for (int mt = 0; mt < 8; ++mt) {
      f32x4 pk;
#pragma unroll
      for (int r = 0; r < 4; ++r) pk[r] = o[mt][r] * inv;
      *(f32x4*)&ob[mt * 16 + g * 4] = pk;
    }
  } else {
    f16* sb = oS + ((size_t)task * 64 + wave * 16 + q15) * 128;
#pragma unroll
    for (int mt = 0; mt < 8; ++mt) {
      f16x4 pk;
#pragma unroll
      for (int r = 0; r < 4; ++r) pk[r] = (f16)(o[mt][r] * inv);
      *(f16x4*)&sb[mt * 16 + g * 4] = pk;
    }
  }
}

// ---------------------------------------------------------------------------
// Kernel 3: combine the two parity partials per task (flash merge), in-place.
// ---------------------------------------------------------------------------
__global__ __launch_bounds__(256) void combine_kernel(float* __restrict__ out,
                                                      const f16* __restrict__ oS,
                                                      const float* __restrict__ MLs) {
  const int task = blockIdx.x;           // b*32 + qt
  const int b = task >> 5, qt = task & 31;
  const int tid = threadIdx.x;
  const int row = tid >> 2;
  const int cb = (tid & 3) * 32;
  const float m0 = MLs[((size_t)(task * 2 + 0) * 64 + row) * 2 + 0];
  const float l0 = MLs[((size_t)(task * 2 + 0) * 64 + row) * 2 + 1];
  const float m1 = MLs[((size_t)(task * 2 + 1) * 64 + row) * 2 + 0];
  const float l1 = MLs[((size_t)(task * 2 + 1) * 64 + row) * 2 + 1];
  const float Mg = fmaxf(m0, m1);
  const float w0 = l0 * __expf(m0 - Mg);
  const float w1 = l1 * __expf(m1 - Mg);
  const float inv = 1.0f / (w0 + w1);
  float* orow = out + ((size_t)b * T + qt * 64 + row) * H + cb;
  const f16* srow = oS + ((size_t)task * 64 + row) * 128 + cb;
#pragma unroll
  for (int c = 0; c < 32; c += 8) {
    const f16x8 o1 = *(const f16x8*)&srow[c];
    f32x4 a0 = *(const f32x4*)&orow[c];
    f32x4 a1 = *(const f32x4*)&orow[c + 4];
    f32x4 r0, r1;
#pragma unroll
    for (int r = 0; r < 4; ++r) {
      r0[r] = (w0 * a0[r] + w1 * (float)o1[r]) * inv;
      r1[r] = (w0 * a1[r] + w1 * (float)o1[4 + r]) * inv;
    }
    *(f32x4*)&orow[c] = r0;
    *(f32x4*)&orow[c + 4] = r1;
  }
}

// ---------------------------------------------------------------------------
extern "C" void kernel_launch(void* const* d_in, const int* in_sizes, int n_in,
                              void* d_out, int out_size, void* d_ws, size_t ws_size,
                              hipStream_t stream) {
  const float* x  = (const float*)d_in[0];   // fp32 inputs per reference
  const float* Wq = (const float*)d_in[1];
  const float* Wk = (const float*)d_in[2];
  const float* Wv = (const float*)d_in[3];
  float* out = (float*)d_out;                // fp32 output

  f16*  wt  = (f16*)d_ws;                             // 3*H*C fp16
  f16*  qf  = wt + (size_t)3 * H * C;                 // M*H fp16
  f16*  kf  = qf + (size_t)M * H;                     // M*H fp16
  f16*  vf  = kf + (size_t)M * H;                     // M*H fp16 [b][h][t]
  f16*  oS  = vf + (size_t)M * H;                     // 256*64*128 fp16
  float* MLs = (float*)(oS + (size_t)256 * 64 * 128); // 256*2*64*2 f32

  kwt<<<dim3(C / 32, H / 32, 3), 256, 0, stream>>>(Wq, Wk, Wv, wt);
  proj_kernel<<<dim3(M / 64, 3), 256, 0, stream>>>(x, wt, qf, kf, vf);
  attn_kernel<<<512, 256, 0, stream>>>(qf, kf, vf, out, oS, MLs);
  combine_kernel<<<256, 256, 0, stream>>>(out, oS, MLs);
}